// Round 8
// baseline (49731.271 us; speedup 1.0000x reference)
//
#include <hip/hip_runtime.h>
#include <math.h>

#define N 64
#define TSTR 65   // transpose-buffer stride

typedef float f32x2 __attribute__((ext_vector_type(2)));
typedef unsigned int u32x2v __attribute__((ext_vector_type(2)));

__device__ __forceinline__ float bperm(int byteaddr, float v) {
    return __int_as_float(__builtin_amdgcn_ds_bpermute(byteaddr, __float_as_int(v)));
}
__device__ __forceinline__ float rlane(float v, int k) {   // uniform k -> v_readlane
    return __int_as_float(__builtin_amdgcn_readlane(__float_as_int(v), k));
}
__device__ __forceinline__ f32x2 pkfma(f32x2 a, f32x2 b, f32x2 c) {   // v_pk_fma_f32
    return __builtin_elementwise_fma(a, b, c);
}

// ---- cross-lane XOR exchange, runtime-probed --------------------------------
// DPP handles xor masks 1..15 (quad_perm 0xB1/0x4E/0x1B, row_half_mirror 0x141,
// row_ror:8 0x128, row_mirror 0x140 + compositions). Bits 4/5 have three
// candidate implementations whose correctness is PROBED at runtime:
//   mode 1: permlane16/32_swap single call, crossed return
//   mode 0: permlane16/32_swap 2-call sequence (documented odd/even semantics)
//   mode 2: DPP for m&15 + ONE ds_bpermute for the m&48 residue
//   mode 3: pure ds_bpermute for everything (always correct; last resort)
template <int CTRL>
__device__ __forceinline__ float fdpp(float v) {
    return __int_as_float(__builtin_amdgcn_update_dpp(
        __float_as_int(v), __float_as_int(v), CTRL, 0xF, 0xF, false));
}
template <int CTRL, int CNT>
__device__ __forceinline__ void dppN(f32x2 (&t)[CNT], const f32x2 (&s)[CNT]) {
#pragma unroll
    for (int i = 0; i < CNT; ++i) {
        t[i].x = fdpp<CTRL>(s[i].x);
        t[i].y = fdpp<CTRL>(s[i].y);
    }
}

#if __has_builtin(__builtin_amdgcn_permlane16_swap)
__device__ __forceinline__ f32x2 pl16_m0(f32x2 v) {
    u32x2v s1 = __builtin_amdgcn_permlane16_swap(__float_as_uint(v.x), __float_as_uint(v.y), false, false);
    u32x2v s2 = __builtin_amdgcn_permlane16_swap(s1.y, s1.x, false, false);
    return (f32x2){__uint_as_float(s2.x), __uint_as_float(s2.y)};
}
__device__ __forceinline__ f32x2 pl16_m1(f32x2 v) {
    u32x2v s1 = __builtin_amdgcn_permlane16_swap(__float_as_uint(v.x), __float_as_uint(v.y), false, false);
    return (f32x2){__uint_as_float(s1.y), __uint_as_float(s1.x)};
}
#else
__device__ __forceinline__ f32x2 pl16_m0(f32x2 v) { return v; }   // probe rejects
__device__ __forceinline__ f32x2 pl16_m1(f32x2 v) { return v; }
#endif
#if __has_builtin(__builtin_amdgcn_permlane32_swap)
__device__ __forceinline__ f32x2 pl32_m0(f32x2 v) {
    u32x2v s1 = __builtin_amdgcn_permlane32_swap(__float_as_uint(v.x), __float_as_uint(v.y), false, false);
    u32x2v s2 = __builtin_amdgcn_permlane32_swap(s1.y, s1.x, false, false);
    return (f32x2){__uint_as_float(s2.x), __uint_as_float(s2.y)};
}
__device__ __forceinline__ f32x2 pl32_m1(f32x2 v) {
    u32x2v s1 = __builtin_amdgcn_permlane32_swap(__float_as_uint(v.x), __float_as_uint(v.y), false, false);
    return (f32x2){__uint_as_float(s1.y), __uint_as_float(s1.x)};
}
#else
__device__ __forceinline__ f32x2 pl32_m0(f32x2 v) { return v; }
__device__ __forceinline__ f32x2 pl32_m1(f32x2 v) { return v; }
#endif

// t = column of lane^m (element-wise lane permute of g). Same templated body
// serves the runtime probe (CNT=1) and the hot loop (CNT=32) -> the probe
// validates exactly the code the solver runs.
template <int CNT>
__device__ __forceinline__ void xchgN(f32x2 (&t)[CNT], const f32x2 (&g)[CNT],
                                      int m, int mode, int lane) {
    if (mode >= 3) {                     // everything via bpermute (verified in R2)
        int ax = (lane ^ m) << 2;
#pragma unroll
        for (int i = 0; i < CNT; ++i) {
            t[i].x = bperm(ax, g[i].x);
            t[i].y = bperm(ax, g[i].y);
        }
        return;
    }
    switch (m & 15) {   // wave-uniform switch
        case 0:
#pragma unroll
            for (int i = 0; i < CNT; ++i) t[i] = g[i];
            break;
        case 1:  dppN<0xB1>(t, g); break;                      // quad[1,0,3,2]
        case 2:  dppN<0x4E>(t, g); break;                      // quad[2,3,0,1]
        case 3:  dppN<0x1B>(t, g); break;                      // quad[3,2,1,0]
        case 4:  dppN<0x141>(t, g); dppN<0x1B>(t, t); break;   // 7^3
        case 5:  dppN<0x141>(t, g); dppN<0x4E>(t, t); break;   // 7^2
        case 6:  dppN<0x141>(t, g); dppN<0xB1>(t, t); break;   // 7^1
        case 7:  dppN<0x141>(t, g); break;                     // row_half_mirror
        case 8:  dppN<0x128>(t, g); break;                     // row_ror:8
        case 9:  dppN<0x128>(t, g); dppN<0xB1>(t, t); break;   // 8^1
        case 10: dppN<0x128>(t, g); dppN<0x4E>(t, t); break;   // 8^2
        case 11: dppN<0x128>(t, g); dppN<0x1B>(t, t); break;   // 8^3
        case 12: dppN<0x140>(t, g); dppN<0x1B>(t, t); break;   // 15^3
        case 13: dppN<0x140>(t, g); dppN<0x4E>(t, t); break;   // 15^2
        case 14: dppN<0x140>(t, g); dppN<0xB1>(t, t); break;   // 15^1
        case 15: dppN<0x140>(t, g); break;                     // row_mirror
    }
    if (mode == 2) {                     // one bpermute for the whole 48-residue
        if (m & 48) {
            int ax = (lane ^ (m & 48)) << 2;
#pragma unroll
            for (int i = 0; i < CNT; ++i) {
                t[i].x = bperm(ax, t[i].x);
                t[i].y = bperm(ax, t[i].y);
            }
        }
        return;
    }
    if (m & 16) {
        if (mode == 1) {
#pragma unroll
            for (int i = 0; i < CNT; ++i) t[i] = pl16_m1(t[i]);
        } else {
#pragma unroll
            for (int i = 0; i < CNT; ++i) t[i] = pl16_m0(t[i]);
        }
    }
    if (m & 32) {
        if (mode == 1) {
#pragma unroll
            for (int i = 0; i < CNT; ++i) t[i] = pl32_m1(t[i]);
        } else {
#pragma unroll
            for (int i = 0; i < CNT; ++i) t[i] = pl32_m0(t[i]);
        }
    }
}

// Exhaustive runtime probe: first mode whose exchange is exact for ALL m wins.
__device__ int probe_xchg_mode(int lane) {
    f32x2 src[1];
    src[0] = (f32x2){(float)lane, (float)(lane + 100)};
#pragma clang loop unroll(disable)
    for (int oi = 0; oi < 3; ++oi) {
        int mode = (oi == 0) ? 1 : (oi == 1) ? 0 : 2;   // prefer cheapest
        int ok = 1;
#pragma clang loop unroll(disable)
        for (int m = 1; m < 64; ++m) {
            f32x2 t[1];
            xchgN(t, src, m, mode, lane);
            int p = lane ^ m;
            ok &= (t[0].x == (float)p) & (t[0].y == (float)(p + 100));
        }
        if (__all(ok)) return mode;
    }
    return 3;   // pure-bpermute floor (always correct)
}

// ---- one-sided Jacobi, one wave per matrix ----------------------------------
// Lane j holds full column j in g2[32]. Partner column via xchgN (probed mode);
// d of partner via one ds_bpermute. Pair-dot computed redundantly on both
// partner lanes with identical fma order -> bitwise identical -> wave-uniform
// rotation decisions. Columns live in VGPRs; no write-back.
__device__ float jacobi_reg(f32x2 (&g2)[32], int lane, int mode, int max_sweeps) {
    float d = 0.f;
#pragma clang loop unroll(disable)
    for (int s = 0; s < max_sweeps; ++s) {
        {   // d = ||col||^2 in-lane
            f32x2 na = {0.f, 0.f}, nb = {0.f, 0.f}, nc = {0.f, 0.f}, nd = {0.f, 0.f};
#pragma unroll
            for (int i = 0; i < 8; ++i) {
                na = pkfma(g2[4 * i + 0], g2[4 * i + 0], na);
                nb = pkfma(g2[4 * i + 1], g2[4 * i + 1], nb);
                nc = pkfma(g2[4 * i + 2], g2[4 * i + 2], nc);
                nd = pkfma(g2[4 * i + 3], g2[4 * i + 3], nd);
            }
            f32x2 ns = (na + nb) + (nc + nd);
            d = ns.x + ns.y;
        }
        int anybad = 0, anybig = 0;
#pragma clang loop unroll(disable)
        for (int m = 1; m < N; ++m) {
            f32x2 t2[32];
            xchgN(t2, g2, m, mode, lane);
            // o = g . t, identical order on both partner lanes
            f32x2 oa = {0.f, 0.f}, ob = {0.f, 0.f}, oc = {0.f, 0.f}, od = {0.f, 0.f};
#pragma unroll
            for (int i = 0; i < 8; ++i) {
                oa = pkfma(g2[4 * i + 0], t2[4 * i + 0], oa);
                ob = pkfma(g2[4 * i + 1], t2[4 * i + 1], ob);
                oc = pkfma(g2[4 * i + 2], t2[4 * i + 2], oc);
                od = pkfma(g2[4 * i + 3], t2[4 * i + 3], od);
            }
            f32x2 os = (oa + ob) + (oc + od);
            float o = os.x + os.y;
            float doth = bperm((lane ^ m) << 2, d);
            bool is_lo = lane < (lane ^ m);
            float dp = is_lo ? d : doth;
            float dq = is_lo ? doth : d;
            float oo = o * o, pq = dp * dq;
            int roundbad = __any(oo > 4e-10f * pq);
            anybad |= roundbad;
            anybig |= __any(oo > 1e-7f * pq);
            if (!roundbad) continue;         // wave-uniform: skip rotation
            bool skip = oo <= (1e-24f * pq);
            float osafe = skip ? 1.0f : o;
            float theta = (dq - dp) * 0.5f * __builtin_amdgcn_rcpf(osafe);
            float tt = -copysignf(
                __builtin_amdgcn_rcpf(fabsf(theta) + sqrtf(fmaf(theta, theta, 1.0f))),
                theta);
            float cc = rsqrtf(fmaf(tt, tt, 1.0f));
            float sv = tt * cc;
            cc = skip ? 1.0f : cc;
            sv = skip ? 0.0f : sv;
            float c2 = cc * cc, s2 = sv * sv, cso = 2.0f * cc * sv * o;
            d = is_lo ? fmaf(c2, dp, fmaf(s2, dq, cso))
                      : fmaf(s2, dp, fmaf(c2, dq, -cso));
            d = fmaxf(d, 1e-30f);
            float ss = is_lo ? sv : -sv;
            f32x2 cc2 = {cc, cc}, ss2 = {ss, ss};
#pragma unroll
            for (int i = 0; i < 32; ++i) g2[i] = pkfma(ss2, t2[i], g2[i] * cc2);
        }
        if (!anybad || !anybig) break;
    }
    f32x2 na = {0.f, 0.f}, nb = {0.f, 0.f};
#pragma unroll
    for (int i = 0; i < 16; ++i) {
        na = pkfma(g2[2 * i], g2[2 * i], na);
        nb = pkfma(g2[2 * i + 1], g2[2 * i + 1], nb);
    }
    f32x2 ns = na + nb;
    return ns.x + ns.y;
}

// out[:,lane] = sum_k coef_k g_k * G[lane][k]; G^T row via shared smem buffer.
__device__ void recon_store(const f32x2 (&g2)[32], float coef, int lane,
                            float* __restrict__ smem, float* __restrict__ outp) {
#pragma unroll
    for (int i = 0; i < 32; ++i) {       // smem[r*TSTR+c] = G[r][c]
        smem[(2 * i) * TSTR + lane]     = g2[i].x;
        smem[(2 * i + 1) * TSTR + lane] = g2[i].y;
    }
    f32x2 acc[32];
#pragma unroll
    for (int i = 0; i < 32; ++i) acc[i] = (f32x2){0.f, 0.f};
#pragma clang loop unroll(disable)
    for (int k = 0; k < N; ++k) {
        float wk = rlane(coef, k) * smem[lane * TSTR + k];   // coef_k * G[lane][k]
        f32x2 wk2 = {wk, wk};
#pragma unroll
        for (int i = 0; i < 32; ++i) {
            f32x2 bc = {rlane(g2[i].x, k), rlane(g2[i].y, k)};
            acc[i] = pkfma(bc, wk2, acc[i]);
        }
    }
#pragma unroll
    for (int i = 0; i < 32; ++i) {
        outp[(size_t)(2 * i) * N + lane]     = acc[i].x;
        outp[(size_t)(2 * i + 1) * N + lane] = acc[i].y;
    }
}

// Kernel A: R_c = ((1-psi) W_c + psi I)^{-1/2}; one WAVE per channel.
__global__ __launch_bounds__(128, 3) void prep_R(const float* __restrict__ wgt,
                                                 float* __restrict__ Rws, int C) {
    __shared__ float smem[N * TSTR];
    int tid = threadIdx.x, wid = tid >> 6, lane = tid & 63;
    int mode = probe_xchg_mode(lane);
    int c = blockIdx.x * 2 + wid;
    if (c >= C) c = 0;                   // duplicate work, benign identical store
    c = __builtin_amdgcn_readfirstlane(c);
    const float* __restrict__ W = wgt + (size_t)c * (N * N);
    f32x2 g2[32];
#pragma unroll
    for (int i = 0; i < 32; ++i) {
        g2[i].x = 0.999f * W[(2 * i) * N + lane]     + ((2 * i)     == lane ? 0.001f : 0.f);
        g2[i].y = 0.999f * W[(2 * i + 1) * N + lane] + ((2 * i + 1) == lane ? 0.001f : 0.f);
    }
    float d = jacobi_reg(g2, lane, mode, 15);
    float coef = sqrtf(rsqrtf(d)) / d;   // f = lambda^{-1/2} -> coef = d^{-5/4}
#pragma unroll
    for (int w = 0; w < 2; ++w) {        // shared smem: serialize the two waves
        if (wid == w) recon_store(g2, coef, lane, smem, Rws + (size_t)c * (N * N));
        __syncthreads();
    }
}

// Kernel B: per (b,c): M = R_c Theta_b R_c -> symmetrize -> recondition -> log.
// One WAVE per (b,c); congruence in registers; LDS only for 2 transposes.
__global__ __launch_bounds__(128, 3) void tangent_log(const float* __restrict__ inp,
                                                      const float* __restrict__ Rws,
                                                      float* __restrict__ out, int total) {
    __shared__ float smem[N * TSTR];
    int tid = threadIdx.x, wid = tid >> 6, lane = tid & 63;
    int mode = probe_xchg_mode(lane);
    int midx = blockIdx.x * 2 + wid;
    if (midx >= total) midx = 0;         // duplicate work, benign identical store
    midx = __builtin_amdgcn_readfirstlane(midx);
    int b = midx >> 2, c = midx & 3;
    const float* __restrict__ Th = inp + (size_t)b * (N * N);
    const float* __restrict__ Rc = Rws + (size_t)c * (N * N);

    // r = column `lane` of R (R symmetric; coalesced b32 loads)
    f32x2 r[32];
#pragma unroll
    for (int k = 0; k < 32; ++k)
        r[k] = (f32x2){Rc[(2 * k) * N + lane], Rc[(2 * k + 1) * N + lane]};

    // ucol = (Theta * R)[:, lane] -- registers only
    f32x2 ucol[32];
#pragma clang loop unroll(disable)
    for (int i = 0; i < 32; ++i) {
        const float4* __restrict__ r0 = (const float4*)(Th + (size_t)(2 * i) * N);
        const float4* __restrict__ r1 = (const float4*)(Th + (size_t)(2 * i + 1) * N);
        f32x2 a0 = {0.f, 0.f}, b0 = {0.f, 0.f}, a1 = {0.f, 0.f}, b1 = {0.f, 0.f};
#pragma unroll
        for (int q = 0; q < 16; ++q) {
            float4 v0 = r0[q], v1 = r1[q];
            a0 = pkfma((f32x2){v0.x, v0.y}, r[2 * q], a0);
            b0 = pkfma((f32x2){v0.z, v0.w}, r[2 * q + 1], b0);
            a1 = pkfma((f32x2){v1.x, v1.y}, r[2 * q], a1);
            b1 = pkfma((f32x2){v1.z, v1.w}, r[2 * q + 1], b1);
        }
        f32x2 s0 = a0 + b0, s1 = a1 + b1;
        ucol[i] = (f32x2){s0.x + s0.y, s1.x + s1.y};
    }
    // mcol = (R * U)[:, lane] -- registers only
    f32x2 mcol[32];
#pragma clang loop unroll(disable)
    for (int i = 0; i < 32; ++i) {
        const float4* __restrict__ r0 = (const float4*)(Rc + (size_t)(2 * i) * N);
        const float4* __restrict__ r1 = (const float4*)(Rc + (size_t)(2 * i + 1) * N);
        f32x2 a0 = {0.f, 0.f}, b0 = {0.f, 0.f}, a1 = {0.f, 0.f}, b1 = {0.f, 0.f};
#pragma unroll
        for (int q = 0; q < 16; ++q) {
            float4 v0 = r0[q], v1 = r1[q];
            a0 = pkfma((f32x2){v0.x, v0.y}, ucol[2 * q], a0);
            b0 = pkfma((f32x2){v0.z, v0.w}, ucol[2 * q + 1], b0);
            a1 = pkfma((f32x2){v1.x, v1.y}, ucol[2 * q], a1);
            b1 = pkfma((f32x2){v1.z, v1.w}, ucol[2 * q + 1], b1);
        }
        f32x2 s0 = a0 + b0, s1 = a1 + b1;
        mcol[i] = (f32x2){s0.x + s0.y, s1.x + s1.y};
    }
    // symmetrize via shared transpose buffer, serialized between the 2 waves
    f32x2 g2[32];
#pragma unroll
    for (int w = 0; w < 2; ++w) {
        if (wid == w) {
#pragma unroll
            for (int i = 0; i < 32; ++i) {               // smem[r*TSTR+c] = M[r][c]
                smem[(2 * i) * TSTR + lane]     = mcol[i].x;
                smem[(2 * i + 1) * TSTR + lane] = mcol[i].y;
            }
#pragma unroll
            for (int i = 0; i < 32; ++i) {
                float ta = smem[lane * TSTR + 2 * i];     // M[lane][2i]
                float tb = smem[lane * TSTR + 2 * i + 1];
                g2[i].x = 0.999f * (0.5f * (mcol[i].x + ta)) + ((2 * i)     == lane ? 0.001f : 0.f);
                g2[i].y = 0.999f * (0.5f * (mcol[i].y + tb)) + ((2 * i + 1) == lane ? 0.001f : 0.f);
            }
        }
        __syncthreads();
    }

    float d = jacobi_reg(g2, lane, mode, 15);
    float coef = 0.5f * logf(d) / d;     // f = log(lambda) = 0.5*log(d)
    __syncthreads();                     // both jacobis done; smem free for recon
#pragma unroll
    for (int w = 0; w < 2; ++w) {
        if (wid == w) recon_store(g2, coef, lane, smem, out + (size_t)midx * (N * N));
        __syncthreads();
    }
}

extern "C" void kernel_launch(void* const* d_in, const int* in_sizes, int n_in,
                              void* d_out, int out_size, void* d_ws, size_t ws_size,
                              hipStream_t stream) {
    const float* inp = (const float*)d_in[0];   // [B,64,64] f32
    const float* wgt = (const float*)d_in[1];   // [C,64,64] f32
    float* out = (float*)d_out;                 // [B,C,64,64] f32
    float* Rws = (float*)d_ws;                  // C*64*64 floats scratch

    int B = in_sizes[0] / (N * N);
    int C = in_sizes[1] / (N * N);

    hipLaunchKernelGGL(prep_R, dim3((C + 1) / 2), dim3(128), 0, stream, wgt, Rws, C);
    hipLaunchKernelGGL(tangent_log, dim3((B * C + 1) / 2), dim3(128), 0, stream,
                       inp, Rws, out, B * C);
}